// Round 1
// baseline (9000.829 us; speedup 1.0000x reference)
//
#include <hip/hip_runtime.h>
#include <math.h>

#define SEQ    8192
#define EMBD   256
#define HD     128
#define GATES  512
#define NTAGS  14
#define TAG_START 12
#define TAG_STOP  13
#define NEGV   (-10000.0f)

// ---- ws layout (float offsets) ----
static constexpr size_t OFF_X     = 0;                               // [SEQ][EMBD]
static constexpr size_t OFF_WT    = OFF_X + (size_t)SEQ * EMBD;      // [EMBD][1024]
static constexpr size_t OFF_BSUM  = OFF_WT + (size_t)EMBD * 1024;    // [1024]
static constexpr size_t OFF_GF    = OFF_BSUM + 1024;                 // [SEQ+2][GATES]
static constexpr size_t OFF_GB    = OFF_GF + (size_t)(SEQ + 2) * GATES;
static constexpr size_t OFF_HF    = OFF_GB + (size_t)(SEQ + 2) * GATES; // [SEQ][HD]
static constexpr size_t OFF_HB    = OFF_HF + (size_t)SEQ * HD;          // [SEQ][HD]
static constexpr size_t OFF_FEATS = OFF_HB + (size_t)SEQ * HD;          // [SEQ+8][16]
static constexpr size_t OFF_BP    = OFF_FEATS + (size_t)(SEQ + 8) * 16; // uchar[SEQ][16]
// total ≈ 49.6 MiB of d_ws

__device__ __forceinline__ float fast_sig(float x) {
  return 1.0f / (1.0f + __expf(-x));
}
__device__ __forceinline__ float fast_tanh(float x) {
  float ax = fabsf(x);
  float e = __expf(-2.0f * ax);
  float m = (1.0f - e) / (1.0f + e);
  return copysignf(m, x);
}
__device__ __forceinline__ float bcast_lane(float x, int lane) {
  return __int_as_float(__builtin_amdgcn_readlane(__float_as_int(x), lane));
}

// barrier that waits LDS only (lgkmcnt), NOT vmcnt -> global prefetch stays in flight
__device__ __forceinline__ void lds_barrier() {
  __builtin_amdgcn_sched_barrier(0);
  asm volatile("s_waitcnt lgkmcnt(0)" ::: "memory");
  __builtin_amdgcn_s_barrier();
  __builtin_amdgcn_sched_barrier(0);
}

// argmax over 14 values, first-index tie-break (matches jnp.argmax)
__device__ __forceinline__ void argmax14(const float s[NTAGS], float& bv, int& bi) {
#define MRG(va, ia, vb, ib, vo, io) { bool c_ = (vb) > (va); (vo) = c_ ? (vb) : (va); (io) = c_ ? (ib) : (ia); }
  float v0, v1, v2, v3, v4, v5, v6; int i0, i1, i2, i3, i4, i5, i6;
  MRG(s[0], 0, s[1], 1, v0, i0); MRG(s[2], 2, s[3], 3, v1, i1);
  MRG(s[4], 4, s[5], 5, v2, i2); MRG(s[6], 6, s[7], 7, v3, i3);
  MRG(s[8], 8, s[9], 9, v4, i4); MRG(s[10], 10, s[11], 11, v5, i5);
  MRG(s[12], 12, s[13], 13, v6, i6);
  float w0, w1, w2; int j0, j1, j2;
  MRG(v0, i0, v1, i1, w0, j0); MRG(v2, i2, v3, i3, w1, j1); MRG(v4, i4, v5, i5, w2, j2);
  float x0, x1; int y0, y1;
  MRG(w0, j0, w1, j1, x0, y0); MRG(w2, j2, v6, i6, x1, y1);
  MRG(x0, y0, x1, y1, bv, bi);
#undef MRG
}

// ---------------- prep: W transpose-pack + bias sums ----------------
__global__ void prep_k(const float* __restrict__ wihf, const float* __restrict__ wihb,
                       const float* __restrict__ bihf, const float* __restrict__ bhhf,
                       const float* __restrict__ bihb, const float* __restrict__ bhhb,
                       float* __restrict__ WT, float* __restrict__ bsum) {
  if (blockIdx.x < 1024) {
    int e = blockIdx.x * 256 + threadIdx.x;     // e over [EMBD*1024)
    int k = e >> 10, c = e & 1023;
    WT[e] = (c < GATES) ? wihf[(size_t)c * EMBD + k] : wihb[(size_t)(c - GATES) * EMBD + k];
  } else {
    for (int i = 0; i < 4; ++i) {
      int c = threadIdx.x + i * 256;
      bsum[c] = (c < GATES) ? (bihf[c] + bhhf[c]) : (bihb[c - GATES] + bhhb[c - GATES]);
    }
  }
}

// ---------------- embedding gather ----------------
__global__ void gather_k(const int* __restrict__ sent, const float* __restrict__ emb,
                         float* __restrict__ X) {
  int t = blockIdx.x;
  int row = sent[t];
  ((float4*)(X + (size_t)t * EMBD))[threadIdx.x] =
      ((const float4*)(emb + (size_t)row * EMBD))[threadIdx.x];
}

// ---------------- input-projection GEMM: G = X @ W^T + bsum ----------------
__global__ __launch_bounds__(256) void gemm_k(const float* __restrict__ X,
                                              const float* __restrict__ WT,
                                              const float* __restrict__ bsum,
                                              float* __restrict__ Gf, float* __restrict__ Gb) {
  __shared__ __align__(16) float As[32][68];   // [k][m], padded stride (16B aligned, low conflict)
  __shared__ __align__(16) float Bs[32][64];   // [k][n]
  const int tid = threadIdx.x;
  const int cb = blockIdx.x * 64;              // 0..960
  const int tb = blockIdx.y * 64;
  const bool flip = (cb >= GATES);
  const int ty = tid >> 4, tx = tid & 15;
  float acc[4][4] = {};

  const int r  = tid >> 2;                     // A-stage: row 0..63
  const int kq = (tid & 3) * 8;                // 8 k's
  const int kB = tid >> 3;                     // B-stage: k 0..31
  const int n8 = (tid & 7) * 8;

  const int trow = tb + r;
  const int src = flip ? (SEQ - 1 - trow) : trow;

  for (int k0 = 0; k0 < EMBD; k0 += 32) {
    const float* xp = X + (size_t)src * EMBD + k0 + kq;
    float4 xa = *(const float4*)xp;
    float4 xb = *(const float4*)(xp + 4);
    As[kq + 0][r] = xa.x; As[kq + 1][r] = xa.y; As[kq + 2][r] = xa.z; As[kq + 3][r] = xa.w;
    As[kq + 4][r] = xb.x; As[kq + 5][r] = xb.y; As[kq + 6][r] = xb.z; As[kq + 7][r] = xb.w;
    const float* wp = WT + (size_t)(k0 + kB) * 1024 + cb + n8;
    *(float4*)&Bs[kB][n8]     = *(const float4*)wp;
    *(float4*)&Bs[kB][n8 + 4] = *(const float4*)(wp + 4);
    __syncthreads();
    #pragma unroll
    for (int k = 0; k < 32; ++k) {
      float4 av = *(const float4*)&As[k][ty * 4];
      float4 bv = *(const float4*)&Bs[k][tx * 4];
      acc[0][0] = fmaf(av.x, bv.x, acc[0][0]); acc[0][1] = fmaf(av.x, bv.y, acc[0][1]);
      acc[0][2] = fmaf(av.x, bv.z, acc[0][2]); acc[0][3] = fmaf(av.x, bv.w, acc[0][3]);
      acc[1][0] = fmaf(av.y, bv.x, acc[1][0]); acc[1][1] = fmaf(av.y, bv.y, acc[1][1]);
      acc[1][2] = fmaf(av.y, bv.z, acc[1][2]); acc[1][3] = fmaf(av.y, bv.w, acc[1][3]);
      acc[2][0] = fmaf(av.z, bv.x, acc[2][0]); acc[2][1] = fmaf(av.z, bv.y, acc[2][1]);
      acc[2][2] = fmaf(av.z, bv.z, acc[2][2]); acc[2][3] = fmaf(av.z, bv.w, acc[2][3]);
      acc[3][0] = fmaf(av.w, bv.x, acc[3][0]); acc[3][1] = fmaf(av.w, bv.y, acc[3][1]);
      acc[3][2] = fmaf(av.w, bv.z, acc[3][2]); acc[3][3] = fmaf(av.w, bv.w, acc[3][3]);
    }
    __syncthreads();
  }
  float4 bz = *(const float4*)&bsum[cb + tx * 4];
  #pragma unroll
  for (int mm = 0; mm < 4; ++mm) {
    int t = tb + ty * 4 + mm;
    float4 v = { acc[mm][0] + bz.x, acc[mm][1] + bz.y, acc[mm][2] + bz.z, acc[mm][3] + bz.w };
    if (!flip) *(float4*)&Gf[(size_t)t * GATES + cb + tx * 4] = v;
    else       *(float4*)&Gb[(size_t)t * GATES + (cb - GATES) + tx * 4] = v;
  }
}

// ---------------- the serial LSTM recurrence (1 block per direction) ----------------
__global__ __launch_bounds__(512, 2) void lstm_k(
    const float* __restrict__ whhf, const float* __restrict__ whhb,
    const float* __restrict__ Gf, const float* __restrict__ Gb,
    float* __restrict__ HF, float* __restrict__ HB) {
  const int dir = blockIdx.x;
  const float* __restrict__ G    = dir ? Gb : Gf;
  float* __restrict__ Hout       = dir ? HB : HF;
  const float* __restrict__ whh  = dir ? whhb : whhf;
  const int g  = threadIdx.x;     // gate row 0..511, order [i,f,g,o]
  const int j  = g & (HD - 1);
  const int gi = g >> 7;

  float4 w[32];
  {
    const float4* w4 = (const float4*)(whh + (size_t)g * HD);
    #pragma unroll
    for (int kk = 0; kk < 32; ++kk) w[kk] = w4[kk];
  }

  __shared__ __align__(16) float hsh[HD];
  __shared__ __align__(16) float gsh[GATES];

  float c = 0.0f;
  if (g < HD) hsh[g] = 0.0f;
  lds_barrier();

  // 2-deep prefetch of the per-step input projection (stays in flight across raw barriers)
  const float* gp = G + g;
  float gc  = gp[0];
  float gn1 = gp[GATES];
  gp += 2 * GATES;

  for (int t = 0; t < SEQ; ++t) {
    float gcur = gc;
    gc  = gn1;
    gn1 = *gp;              // row t+2 (padded allocation)
    gp += GATES;

    float a0 = gcur, a1 = 0.f, a2 = 0.f, a3 = 0.f;
    const float4* h4 = (const float4*)hsh;
    #pragma unroll
    for (int kk = 0; kk < 32; ++kk) {
      float4 hv = h4[kk];    // wave-uniform address -> LDS broadcast
      float4 wv = w[kk];
      a0 = fmaf(wv.x, hv.x, a0);
      a1 = fmaf(wv.y, hv.y, a1);
      a2 = fmaf(wv.z, hv.z, a2);
      a3 = fmaf(wv.w, hv.w, a3);
    }
    float pre = (a0 + a1) + (a2 + a3);
    float act = (gi == 2) ? fast_tanh(pre) : fast_sig(pre);
    gsh[j * 4 + gi] = act;
    lds_barrier();
    if (g < HD) {
      float4 ga = *(const float4*)&gsh[g * 4];   // (i,f,g,o)
      c = fmaf(ga.y, c, ga.x * ga.z);
      float hj = ga.w * fast_tanh(c);
      hsh[g] = hj;
      int trow = dir ? (SEQ - 1 - t) : t;
      Hout[(size_t)trow * HD + g] = hj;          // fire-and-forget (not drained)
    }
    lds_barrier();
  }
}

// ---------------- tag-space projection: feats = [hf|hb] @ w_tag^T + b_tag ----------------
__global__ void feats_k(const float* __restrict__ HF, const float* __restrict__ HB,
                        const float* __restrict__ wtag, const float* __restrict__ btag,
                        float* __restrict__ feats) {
  const int t = blockIdx.x, l = threadIdx.x;   // 64 lanes
  float2 a = ((const float2*)(HF + (size_t)t * HD))[l];
  float2 b = ((const float2*)(HB + (size_t)t * HD))[l];
  float p[NTAGS];
  #pragma unroll
  for (int n = 0; n < NTAGS; ++n) {
    const float* wr = wtag + (size_t)n * 256;
    float2 w0 = ((const float2*)wr)[l];
    float2 w1 = ((const float2*)(wr + HD))[l];
    p[n] = a.x * w0.x + a.y * w0.y + b.x * w1.x + b.y * w1.y;
  }
  #pragma unroll
  for (int n = 0; n < NTAGS; ++n) {
    float v = p[n];
    for (int off = 32; off > 0; off >>= 1) v += __shfl_down(v, off);
    if (l == 0) feats[(size_t)t * 16 + n] = v + btag[n];
  }
}

// ---------------- Viterbi forward + chunked parallel backtrace ----------------
__global__ __launch_bounds__(1024) void viterbi_k(
    const float* __restrict__ feats, const float* __restrict__ trans,
    unsigned char* __restrict__ bpg, float* __restrict__ out) {
  __shared__ int sh_M[64 * 16];
  __shared__ int sh_B[64];
  __shared__ int sh_best;
  const int tid = threadIdx.x;

  if (tid < 64) {                 // wave 0: serial forward pass, lane n = next-tag
    const int n = tid;
    const bool act = n < NTAGS;
    float Tn[NTAGS];
    #pragma unroll
    for (int p = 0; p < NTAGS; ++p) Tn[p] = act ? trans[n * NTAGS + p] : 0.0f;
    const float Tstop = act ? trans[TAG_STOP * NTAGS + n] : 0.0f;
    float fv = (n == TAG_START) ? 0.0f : NEGV;

    float fbuf[8];                // 8-deep feats prefetch (static indices)
    #pragma unroll
    for (int u = 0; u < 8; ++u) fbuf[u] = act ? feats[(size_t)u * 16 + n] : 0.0f;

    for (int t0 = 0; t0 < SEQ; t0 += 8) {
      #pragma unroll
      for (int u = 0; u < 8; ++u) {
        const int t = t0 + u;
        float ftc = fbuf[u];
        fbuf[u] = act ? feats[(size_t)(t + 8) * 16 + n] : 0.0f;  // padded rows
        float s[NTAGS];
        #pragma unroll
        for (int p = 0; p < NTAGS; ++p) s[p] = bcast_lane(fv, p) + Tn[p];
        float bv; int bi;
        argmax14(s, bv, bi);
        fv = bv + ftc;
        if (act) bpg[(size_t)t * 16 + n] = (unsigned char)bi;
      }
    }
    float tn = fv + Tstop;
    float tv[NTAGS];
    #pragma unroll
    for (int p = 0; p < NTAGS; ++p) tv[p] = bcast_lane(tn, p);
    if (n == 0) {
      float bv; int bi;
      argmax14(tv, bv, bi);
      out[0] = bv;                // score
      sh_best = bi;
    }
  }
  __syncthreads();                // full drain: bpg visible to block
  {                               // phase B: compose 128-step backpointer maps per chunk
    const int c = tid >> 4, k = tid & 15;
    if (c >= 1 && c < 64 && k < NTAGS) {
      int x = k;
      for (int i = 127; i >= 0; --i) x = bpg[((size_t)(c * 128 + i)) * 16 + x];
      sh_M[c * 16 + k] = x;
    }
  }
  __syncthreads();
  if (tid == 0) {                 // phase C: serial walk over 64 chunk boundaries
    int b = sh_best;
    sh_B[63] = b;
    for (int c = 63; c >= 1; --c) { b = sh_M[c * 16 + b]; sh_B[c - 1] = b; }
  }
  __syncthreads();
  if (tid < 64) {                 // phase D: chunks re-walk in parallel, emit path
    const int c = tid;
    int x = sh_B[c];
    out[1 + c * 128 + 127] = (float)x;
    for (int i = 127; i >= 1; --i) {
      x = bpg[((size_t)(c * 128 + i)) * 16 + x];
      out[1 + c * 128 + i - 1] = (float)x;
    }
  }
}

extern "C" void kernel_launch(void* const* d_in, const int* in_sizes, int n_in,
                              void* d_out, int out_size, void* d_ws, size_t ws_size,
                              hipStream_t stream) {
  (void)in_sizes; (void)n_in; (void)out_size; (void)ws_size;
  const int*   sent = (const int*)d_in[0];
  const float* emb  = (const float*)d_in[1];
  const float* wihf = (const float*)d_in[2];
  const float* whhf = (const float*)d_in[3];
  const float* bihf = (const float*)d_in[4];
  const float* bhhf = (const float*)d_in[5];
  const float* wihb = (const float*)d_in[6];
  const float* whhb = (const float*)d_in[7];
  const float* bihb = (const float*)d_in[8];
  const float* bhhb = (const float*)d_in[9];
  const float* wtag = (const float*)d_in[10];
  const float* btag = (const float*)d_in[11];
  const float* trans = (const float*)d_in[12];

  float* ws = (float*)d_ws;
  float* X    = ws + OFF_X;
  float* WT   = ws + OFF_WT;
  float* BS   = ws + OFF_BSUM;
  float* Gf   = ws + OFF_GF;
  float* Gb   = ws + OFF_GB;
  float* HF   = ws + OFF_HF;
  float* HB   = ws + OFF_HB;
  float* FE   = ws + OFF_FEATS;
  unsigned char* bpg = (unsigned char*)(ws + OFF_BP);
  float* out = (float*)d_out;

  prep_k<<<1025, 256, 0, stream>>>(wihf, wihb, bihf, bhhf, bihb, bhhb, WT, BS);
  gather_k<<<SEQ, 64, 0, stream>>>(sent, emb, X);
  gemm_k<<<dim3(16, 128), 256, 0, stream>>>(X, WT, BS, Gf, Gb);
  lstm_k<<<2, 512, 0, stream>>>(whhf, whhb, Gf, Gb, HF, HB);
  feats_k<<<SEQ, 64, 0, stream>>>(HF, HB, wtag, btag, FE);
  viterbi_k<<<1, 1024, 0, stream>>>(FE, trans, bpg, out);
}

// Round 3
// 7917.342 us; speedup vs baseline: 1.1368x; 1.1368x over previous
//
#include <hip/hip_runtime.h>
#include <math.h>

#define SEQ    8192
#define EMBD   256
#define HD     128
#define GATES  512
#define NTAGS  14
#define TAG_START 12
#define TAG_STOP  13
#define NEGV   (-10000.0f)

// ---- ws layout (float offsets) ----
static constexpr size_t OFF_X     = 0;                               // [SEQ][EMBD]
static constexpr size_t OFF_WT    = OFF_X + (size_t)SEQ * EMBD;      // [EMBD][1024]
static constexpr size_t OFF_BSUM  = OFF_WT + (size_t)EMBD * 1024;    // [1024]
static constexpr size_t OFF_GF    = OFF_BSUM + 1024;                 // [SEQ+2][GATES] quad-layout
static constexpr size_t OFF_GB    = OFF_GF + (size_t)(SEQ + 2) * GATES;
static constexpr size_t OFF_HF    = OFF_GB + (size_t)(SEQ + 2) * GATES; // [SEQ][HD]
static constexpr size_t OFF_HB    = OFF_HF + (size_t)SEQ * HD;          // [SEQ][HD]
static constexpr size_t OFF_FEATS = OFF_HB + (size_t)SEQ * HD;          // [SEQ+8][16]
static constexpr size_t OFF_BP    = OFF_FEATS + (size_t)(SEQ + 8) * 16; // uchar[SEQ][16]

#define LOG2E  1.4426950408889634f
#define LOG2E2 2.8853900817779268f

__device__ __forceinline__ float fast_rcp(float x) { return __builtin_amdgcn_rcpf(x); }
__device__ __forceinline__ float bcast_lane(float x, int lane) {
  return __int_as_float(__builtin_amdgcn_readlane(__float_as_int(x), lane));
}
// DPP quad_perm broadcast: lane k of each 4-lane quad -> all 4 lanes (pure VALU)
template<int CTRL>
__device__ __forceinline__ float quad_bcast(float x) {
  int xi = __float_as_int(x);
  int r = __builtin_amdgcn_update_dpp(xi, xi, CTRL, 0xF, 0xF, false);
  return __int_as_float(r);
}

// barrier that waits LDS only (lgkmcnt), NOT vmcnt -> global prefetch stays in flight
__device__ __forceinline__ void lds_barrier() {
  __builtin_amdgcn_sched_barrier(0);
  asm volatile("s_waitcnt lgkmcnt(0)" ::: "memory");
  __builtin_amdgcn_s_barrier();
  __builtin_amdgcn_sched_barrier(0);
}

// argmax over 14 values, first-index tie-break (matches jnp.argmax)
__device__ __forceinline__ void argmax14(const float s[NTAGS], float& bv, int& bi) {
#define MRG(va, ia, vb, ib, vo, io) { bool c_ = (vb) > (va); (vo) = c_ ? (vb) : (va); (io) = c_ ? (ib) : (ia); }
  float v0, v1, v2, v3, v4, v5, v6; int i0, i1, i2, i3, i4, i5, i6;
  MRG(s[0], 0, s[1], 1, v0, i0); MRG(s[2], 2, s[3], 3, v1, i1);
  MRG(s[4], 4, s[5], 5, v2, i2); MRG(s[6], 6, s[7], 7, v3, i3);
  MRG(s[8], 8, s[9], 9, v4, i4); MRG(s[10], 10, s[11], 11, v5, i5);
  MRG(s[12], 12, s[13], 13, v6, i6);
  float w0, w1, w2; int j0, j1, j2;
  MRG(v0, i0, v1, i1, w0, j0); MRG(v2, i2, v3, i3, w1, j1); MRG(v4, i4, v5, i5, w2, j2);
  float x0, x1; int y0, y1;
  MRG(w0, j0, w1, j1, x0, y0); MRG(w2, j2, v6, i6, x1, y1);
  MRG(x0, y0, x1, y1, bv, bi);
#undef MRG
}

// ---------------- prep: W transpose-pack (quad-permuted cols) + bias sums ----------------
// column c (quad layout) -> original gate row src = (c&3)*HD + (c>>2)
__global__ void prep_k(const float* __restrict__ wihf, const float* __restrict__ wihb,
                       const float* __restrict__ bihf, const float* __restrict__ bhhf,
                       const float* __restrict__ bihb, const float* __restrict__ bhhb,
                       float* __restrict__ WT, float* __restrict__ bsum) {
  if (blockIdx.x < 1024) {
    int e = blockIdx.x * 256 + threadIdx.x;     // e over [EMBD*1024)
    int k = e >> 10, c = e & 1023;
    int cq = c & 511;
    int src = (cq & 3) * HD + (cq >> 2);
    WT[e] = (c < GATES) ? wihf[(size_t)src * EMBD + k] : wihb[(size_t)src * EMBD + k];
  } else {
    for (int i = 0; i < 4; ++i) {
      int c = threadIdx.x + i * 256;
      int cq = c & 511;
      int src = (cq & 3) * HD + (cq >> 2);
      bsum[c] = (c < GATES) ? (bihf[src] + bhhf[src]) : (bihb[src] + bhhb[src]);
    }
  }
}

// ---------------- embedding gather ----------------
__global__ void gather_k(const int* __restrict__ sent, const float* __restrict__ emb,
                         float* __restrict__ X) {
  int t = blockIdx.x;
  int row = sent[t];
  ((float4*)(X + (size_t)t * EMBD))[threadIdx.x] =
      ((const float4*)(emb + (size_t)row * EMBD))[threadIdx.x];
}

// ---------------- input-projection GEMM: G = X @ W^T + bsum ----------------
__global__ __launch_bounds__(256) void gemm_k(const float* __restrict__ X,
                                              const float* __restrict__ WT,
                                              const float* __restrict__ bsum,
                                              float* __restrict__ Gf, float* __restrict__ Gb) {
  __shared__ __align__(16) float As[32][68];   // [k][m], padded stride
  __shared__ __align__(16) float Bs[32][64];   // [k][n]
  const int tid = threadIdx.x;
  const int cb = blockIdx.x * 64;              // 0..960
  const int tb = blockIdx.y * 64;
  const bool flip = (cb >= GATES);
  const int ty = tid >> 4, tx = tid & 15;
  float acc[4][4] = {};

  const int r  = tid >> 2;                     // A-stage: row 0..63
  const int kq = (tid & 3) * 8;                // 8 k's
  const int kB = tid >> 3;                     // B-stage: k 0..31
  const int n8 = (tid & 7) * 8;

  const int trow = tb + r;
  const int src = flip ? (SEQ - 1 - trow) : trow;

  for (int k0 = 0; k0 < EMBD; k0 += 32) {
    const float* xp = X + (size_t)src * EMBD + k0 + kq;
    float4 xa = *(const float4*)xp;
    float4 xb = *(const float4*)(xp + 4);
    As[kq + 0][r] = xa.x; As[kq + 1][r] = xa.y; As[kq + 2][r] = xa.z; As[kq + 3][r] = xa.w;
    As[kq + 4][r] = xb.x; As[kq + 5][r] = xb.y; As[kq + 6][r] = xb.z; As[kq + 7][r] = xb.w;
    const float* wp = WT + (size_t)(k0 + kB) * 1024 + cb + n8;
    *(float4*)&Bs[kB][n8]     = *(const float4*)wp;
    *(float4*)&Bs[kB][n8 + 4] = *(const float4*)(wp + 4);
    __syncthreads();
    #pragma unroll
    for (int k = 0; k < 32; ++k) {
      float4 av = *(const float4*)&As[k][ty * 4];
      float4 bv = *(const float4*)&Bs[k][tx * 4];
      acc[0][0] = fmaf(av.x, bv.x, acc[0][0]); acc[0][1] = fmaf(av.x, bv.y, acc[0][1]);
      acc[0][2] = fmaf(av.x, bv.z, acc[0][2]); acc[0][3] = fmaf(av.x, bv.w, acc[0][3]);
      acc[1][0] = fmaf(av.y, bv.x, acc[1][0]); acc[1][1] = fmaf(av.y, bv.y, acc[1][1]);
      acc[1][2] = fmaf(av.y, bv.z, acc[1][2]); acc[1][3] = fmaf(av.y, bv.w, acc[1][3]);
      acc[2][0] = fmaf(av.z, bv.x, acc[2][0]); acc[2][1] = fmaf(av.z, bv.y, acc[2][1]);
      acc[2][2] = fmaf(av.z, bv.z, acc[2][2]); acc[2][3] = fmaf(av.z, bv.w, acc[2][3]);
      acc[3][0] = fmaf(av.w, bv.x, acc[3][0]); acc[3][1] = fmaf(av.w, bv.y, acc[3][1]);
      acc[3][2] = fmaf(av.w, bv.z, acc[3][2]); acc[3][3] = fmaf(av.w, bv.w, acc[3][3]);
    }
    __syncthreads();
  }
  float4 bz = *(const float4*)&bsum[cb + tx * 4];
  #pragma unroll
  for (int mm = 0; mm < 4; ++mm) {
    int t = tb + ty * 4 + mm;
    float4 v = { acc[mm][0] + bz.x, acc[mm][1] + bz.y, acc[mm][2] + bz.z, acc[mm][3] + bz.w };
    if (!flip) *(float4*)&Gf[(size_t)t * GATES + cb + tx * 4] = v;
    else       *(float4*)&Gb[(size_t)t * GATES + (cb - GATES) + tx * 4] = v;
  }
}

// ---------------- the serial LSTM recurrence (1 block per direction) ----------------
// Quad layout: thread g -> hidden j = g>>2, gate gi = g&3 (i,f,g,o).
// Gate exchange via DPP quad broadcast (no LDS, no barrier); cell update done
// redundantly by all 4 quad lanes -> exactly ONE barrier per step, with
// double-buffered h in LDS to avoid read/write races across the single barrier.
__global__ __launch_bounds__(512, 2) void lstm_k(
    const float* __restrict__ whhf, const float* __restrict__ whhb,
    const float* __restrict__ Gf, const float* __restrict__ Gb,
    float* __restrict__ HF, float* __restrict__ HB) {
  const int dir = blockIdx.x;
  const float* __restrict__ G   = dir ? Gb : Gf;
  float* __restrict__ Hout      = dir ? HB : HF;
  const float* __restrict__ whh = dir ? whhb : whhf;
  const int g  = threadIdx.x;
  const int j  = g >> 2;        // hidden index 0..127
  const int gi = g & 3;         // gate 0..3 = i,f,g,o
  const bool gi0 = (gi == 0);

  // weight row (original layout) for this (gate, j)
  float4 w[32];
  {
    const float4* w4 = (const float4*)(whh + (size_t)(gi * HD + j) * HD);
    #pragma unroll
    for (int kk = 0; kk < 32; ++kk) w[kk] = w4[kk];
  }

  // unified activation: act = aa * sigmoid-core(pre*mm') + bb
  //   sigmoid: rcp(1+exp2(-x*log2e)); tanh(x) = 2*sig(2x)-1
  const float mm = (gi == 2) ? -LOG2E2 : -LOG2E;
  const float aa = (gi == 2) ? 2.0f : 1.0f;
  const float bb = (gi == 2) ? -1.0f : 0.0f;

  __shared__ __align__(16) float hshA[HD], hshB[HD];
  if (gi0) hshA[j] = 0.0f;

  float cst = 0.0f;

  // 2-deep prefetch of per-step input projection (quad-permuted, coalesced)
  const float* gp = G + g;
  float gc  = gp[0];
  float gn1 = gp[GATES];
  gp += 2 * GATES;

  float* hout = Hout + (size_t)(dir ? (SEQ - 1) : 0) * HD + j;
  const ptrdiff_t hstep = dir ? -(ptrdiff_t)HD : (ptrdiff_t)HD;

  lds_barrier();

  auto step = [&](const float* hrd, float* hwr) {
    float gcur = gc; gc = gn1; gn1 = *gp; gp += GATES;

    float a0 = gcur, a1 = 0.f, a2 = 0.f, a3 = 0.f;
    const float4* h4 = (const float4*)hrd;
    #pragma unroll
    for (int kk = 0; kk < 32; ++kk) {
      float4 hv = h4[kk];      // wave-uniform address -> LDS broadcast
      float4 wv = w[kk];
      a0 = fmaf(wv.x, hv.x, a0);
      a1 = fmaf(wv.y, hv.y, a1);
      a2 = fmaf(wv.z, hv.z, a2);
      a3 = fmaf(wv.w, hv.w, a3);
    }
    float pre = (a0 + a1) + (a2 + a3);
    float act = fmaf(aa, fast_rcp(1.0f + exp2f(pre * mm)), bb);

    float i_ = quad_bcast<0x00>(act);   // lane 0 of quad: input gate
    float f_ = quad_bcast<0x55>(act);   // lane 1: forget
    float g_ = quad_bcast<0xAA>(act);   // lane 2: cell cand (tanh)
    float o_ = quad_bcast<0xFF>(act);   // lane 3: output
    cst = fmaf(f_, cst, i_ * g_);
    float th = fmaf(2.0f, fast_rcp(1.0f + exp2f(cst * -LOG2E2)), -1.0f);
    float hj = o_ * th;
    if (gi0) { hwr[j] = hj; *hout = hj; }   // h store + fire-and-forget global
    hout += hstep;
    lds_barrier();   // the ONLY barrier per step
  };

  for (int t = 0; t < SEQ; t += 2) {
    step(hshA, hshB);
    step(hshB, hshA);
  }
}

// ---------------- tag-space projection: feats = [hf|hb] @ w_tag^T + b_tag ----------------
__global__ void feats_k(const float* __restrict__ HF, const float* __restrict__ HB,
                        const float* __restrict__ wtag, const float* __restrict__ btag,
                        float* __restrict__ feats) {
  const int t = blockIdx.x, l = threadIdx.x;   // 64 lanes
  float2 a = ((const float2*)(HF + (size_t)t * HD))[l];
  float2 b = ((const float2*)(HB + (size_t)t * HD))[l];
  float p[NTAGS];
  #pragma unroll
  for (int n = 0; n < NTAGS; ++n) {
    const float* wr = wtag + (size_t)n * 256;
    float2 w0 = ((const float2*)wr)[l];
    float2 w1 = ((const float2*)(wr + HD))[l];
    p[n] = a.x * w0.x + a.y * w0.y + b.x * w1.x + b.y * w1.y;
  }
  #pragma unroll
  for (int n = 0; n < NTAGS; ++n) {
    float v = p[n];
    for (int off = 32; off > 0; off >>= 1) v += __shfl_down(v, off);
    if (l == 0) feats[(size_t)t * 16 + n] = v + btag[n];
  }
}

// ---------------- Viterbi forward + chunked parallel backtrace ----------------
__global__ __launch_bounds__(1024) void viterbi_k(
    const float* __restrict__ feats, const float* __restrict__ trans,
    unsigned char* __restrict__ bpg, float* __restrict__ out) {
  __shared__ int sh_M[64 * 16];
  __shared__ int sh_B[64];
  __shared__ int sh_best;
  const int tid = threadIdx.x;

  if (tid < 64) {                 // wave 0: serial forward pass, lane n = next-tag
    const int n = tid;
    const bool act = n < NTAGS;
    float Tn[NTAGS];
    #pragma unroll
    for (int p = 0; p < NTAGS; ++p) Tn[p] = act ? trans[n * NTAGS + p] : 0.0f;
    const float Tstop = act ? trans[TAG_STOP * NTAGS + n] : 0.0f;
    float fv = (n == TAG_START) ? 0.0f : NEGV;

    float fbuf[8];                // 8-deep feats prefetch (static indices)
    #pragma unroll
    for (int u = 0; u < 8; ++u) fbuf[u] = act ? feats[(size_t)u * 16 + n] : 0.0f;

    for (int t0 = 0; t0 < SEQ; t0 += 8) {
      #pragma unroll
      for (int u = 0; u < 8; ++u) {
        const int t = t0 + u;
        float ftc = fbuf[u];
        fbuf[u] = act ? feats[(size_t)(t + 8) * 16 + n] : 0.0f;  // padded rows
        float s[NTAGS];
        #pragma unroll
        for (int p = 0; p < NTAGS; ++p) s[p] = bcast_lane(fv, p) + Tn[p];
        float bv; int bi;
        argmax14(s, bv, bi);
        fv = bv + ftc;
        if (act) bpg[(size_t)t * 16 + n] = (unsigned char)bi;
      }
    }
    float tn = fv + Tstop;
    float tv[NTAGS];
    #pragma unroll
    for (int p = 0; p < NTAGS; ++p) tv[p] = bcast_lane(tn, p);
    if (n == 0) {
      float bv; int bi;
      argmax14(tv, bv, bi);
      out[0] = bv;                // score
      sh_best = bi;
    }
  }
  __syncthreads();                // full drain: bpg visible to block
  {                               // phase B: compose 128-step backpointer maps per chunk
    const int c = tid >> 4, k = tid & 15;
    if (c >= 1 && c < 64 && k < NTAGS) {
      int x = k;
      for (int i = 127; i >= 0; --i) x = bpg[((size_t)(c * 128 + i)) * 16 + x];
      sh_M[c * 16 + k] = x;
    }
  }
  __syncthreads();
  if (tid == 0) {                 // phase C: serial walk over 64 chunk boundaries
    int b = sh_best;
    sh_B[63] = b;
    for (int c = 63; c >= 1; --c) { b = sh_M[c * 16 + b]; sh_B[c - 1] = b; }
  }
  __syncthreads();
  if (tid < 64) {                 // phase D: chunks re-walk in parallel, emit path
    const int c = tid;
    int x = sh_B[c];
    out[1 + c * 128 + 127] = (float)x;
    for (int i = 127; i >= 1; --i) {
      x = bpg[((size_t)(c * 128 + i)) * 16 + x];
      out[1 + c * 128 + i - 1] = (float)x;
    }
  }
}

extern "C" void kernel_launch(void* const* d_in, const int* in_sizes, int n_in,
                              void* d_out, int out_size, void* d_ws, size_t ws_size,
                              hipStream_t stream) {
  (void)in_sizes; (void)n_in; (void)out_size; (void)ws_size;
  const int*   sent = (const int*)d_in[0];
  const float* emb  = (const float*)d_in[1];
  const float* wihf = (const float*)d_in[2];
  const float* whhf = (const float*)d_in[3];
  const float* bihf = (const float*)d_in[4];
  const float* bhhf = (const float*)d_in[5];
  const float* wihb = (const float*)d_in[6];
  const float* whhb = (const float*)d_in[7];
  const float* bihb = (const float*)d_in[8];
  const float* bhhb = (const float*)d_in[9];
  const float* wtag = (const float*)d_in[10];
  const float* btag = (const float*)d_in[11];
  const float* trans = (const float*)d_in[12];

  float* ws = (float*)d_ws;
  float* X    = ws + OFF_X;
  float* WT   = ws + OFF_WT;
  float* BS   = ws + OFF_BSUM;
  float* Gf   = ws + OFF_GF;
  float* Gb   = ws + OFF_GB;
  float* HF   = ws + OFF_HF;
  float* HB   = ws + OFF_HB;
  float* FE   = ws + OFF_FEATS;
  unsigned char* bpg = (unsigned char*)(ws + OFF_BP);
  float* out = (float*)d_out;

  prep_k<<<1025, 256, 0, stream>>>(wihf, wihb, bihf, bhhf, bihb, bhhb, WT, BS);
  gather_k<<<SEQ, 64, 0, stream>>>(sent, emb, X);
  gemm_k<<<dim3(16, 128), 256, 0, stream>>>(X, WT, BS, Gf, Gb);
  lstm_k<<<2, 512, 0, stream>>>(whhf, whhb, Gf, Gb, HF, HB);
  feats_k<<<SEQ, 64, 0, stream>>>(HF, HB, wtag, btag, FE);
  viterbi_k<<<1, 1024, 0, stream>>>(FE, trans, bpg, out);
}

// Round 4
// 7019.214 us; speedup vs baseline: 1.2823x; 1.1280x over previous
//
#include <hip/hip_runtime.h>
#include <hip/hip_fp16.h>
#include <math.h>

#define SEQ    8192
#define EMBD   256
#define HD     128
#define GATES  512
#define NTAGS  14
#define TAG_START 12
#define TAG_STOP  13
#define NEGV   (-10000.0f)

// ---- ws layout (float offsets) ----
static constexpr size_t OFF_X     = 0;                               // [SEQ][EMBD]
static constexpr size_t OFF_WT    = OFF_X + (size_t)SEQ * EMBD;      // [EMBD][1024]
static constexpr size_t OFF_BSUM  = OFF_WT + (size_t)EMBD * 1024;    // [1024]
static constexpr size_t OFF_GF    = OFF_BSUM + 1024;                 // [SEQ+2][GATES] quad-layout
static constexpr size_t OFF_GB    = OFF_GF + (size_t)(SEQ + 2) * GATES;
static constexpr size_t OFF_HF    = OFF_GB + (size_t)(SEQ + 2) * GATES; // [SEQ][HD]
static constexpr size_t OFF_HB    = OFF_HF + (size_t)SEQ * HD;          // [SEQ][HD]
static constexpr size_t OFF_FEATS = OFF_HB + (size_t)SEQ * HD;          // [SEQ+8][16]
static constexpr size_t OFF_BP    = OFF_FEATS + (size_t)(SEQ + 8) * 16; // uchar[SEQ][16]

#define LOG2E  1.4426950408889634f
#define LOG2E2 2.8853900817779268f

__device__ __forceinline__ float fast_rcp(float x) { return __builtin_amdgcn_rcpf(x); }
__device__ __forceinline__ float bcast_lane(float x, int lane) {
  return __int_as_float(__builtin_amdgcn_readlane(__float_as_int(x), lane));
}
// DPP quad_perm: returns the quad-permuted value (pure VALU, no LDS)
template<int CTRL>
__device__ __forceinline__ float quad_dpp(float x) {
  int xi = __float_as_int(x);
  int r = __builtin_amdgcn_update_dpp(xi, xi, CTRL, 0xF, 0xF, false);
  return __int_as_float(r);
}

// barrier that waits LDS only (lgkmcnt), NOT vmcnt -> global prefetch stays in flight
__device__ __forceinline__ void lds_barrier() {
  __builtin_amdgcn_sched_barrier(0);
  asm volatile("s_waitcnt lgkmcnt(0)" ::: "memory");
  __builtin_amdgcn_s_barrier();
  __builtin_amdgcn_sched_barrier(0);
}

// argmax over 14 values, first-index tie-break (matches jnp.argmax)
__device__ __forceinline__ void argmax14(const float s[NTAGS], float& bv, int& bi) {
#define MRG(va, ia, vb, ib, vo, io) { bool c_ = (vb) > (va); (vo) = c_ ? (vb) : (va); (io) = c_ ? (ib) : (ia); }
  float v0, v1, v2, v3, v4, v5, v6; int i0, i1, i2, i3, i4, i5, i6;
  MRG(s[0], 0, s[1], 1, v0, i0); MRG(s[2], 2, s[3], 3, v1, i1);
  MRG(s[4], 4, s[5], 5, v2, i2); MRG(s[6], 6, s[7], 7, v3, i3);
  MRG(s[8], 8, s[9], 9, v4, i4); MRG(s[10], 10, s[11], 11, v5, i5);
  MRG(s[12], 12, s[13], 13, v6, i6);
  float w0, w1, w2; int j0, j1, j2;
  MRG(v0, i0, v1, i1, w0, j0); MRG(v2, i2, v3, i3, w1, j1); MRG(v4, i4, v5, i5, w2, j2);
  float x0, x1; int y0, y1;
  MRG(w0, j0, w1, j1, x0, y0); MRG(w2, j2, v6, i6, x1, y1);
  MRG(x0, y0, x1, y1, bv, bi);
#undef MRG
}

// ---------------- prep: W transpose-pack (quad-permuted cols) + bias sums ----------------
// column c (quad layout) -> original gate row src = (c&3)*HD + (c>>2)
__global__ void prep_k(const float* __restrict__ wihf, const float* __restrict__ wihb,
                       const float* __restrict__ bihf, const float* __restrict__ bhhf,
                       const float* __restrict__ bihb, const float* __restrict__ bhhb,
                       float* __restrict__ WT, float* __restrict__ bsum) {
  if (blockIdx.x < 1024) {
    int e = blockIdx.x * 256 + threadIdx.x;     // e over [EMBD*1024)
    int k = e >> 10, c = e & 1023;
    int cq = c & 511;
    int src = (cq & 3) * HD + (cq >> 2);
    WT[e] = (c < GATES) ? wihf[(size_t)src * EMBD + k] : wihb[(size_t)src * EMBD + k];
  } else {
    for (int i = 0; i < 4; ++i) {
      int c = threadIdx.x + i * 256;
      int cq = c & 511;
      int src = (cq & 3) * HD + (cq >> 2);
      bsum[c] = (c < GATES) ? (bihf[src] + bhhf[src]) : (bihb[src] + bhhb[src]);
    }
  }
}

// ---------------- embedding gather ----------------
__global__ void gather_k(const int* __restrict__ sent, const float* __restrict__ emb,
                         float* __restrict__ X) {
  int t = blockIdx.x;
  int row = sent[t];
  ((float4*)(X + (size_t)t * EMBD))[threadIdx.x] =
      ((const float4*)(emb + (size_t)row * EMBD))[threadIdx.x];
}

// ---------------- input-projection GEMM: G = X @ W^T + bsum ----------------
__global__ __launch_bounds__(256) void gemm_k(const float* __restrict__ X,
                                              const float* __restrict__ WT,
                                              const float* __restrict__ bsum,
                                              float* __restrict__ Gf, float* __restrict__ Gb) {
  __shared__ __align__(16) float As[32][68];   // [k][m], padded stride
  __shared__ __align__(16) float Bs[32][64];   // [k][n]
  const int tid = threadIdx.x;
  const int cb = blockIdx.x * 64;              // 0..960
  const int tb = blockIdx.y * 64;
  const bool flip = (cb >= GATES);
  const int ty = tid >> 4, tx = tid & 15;
  float acc[4][4] = {};

  const int r  = tid >> 2;                     // A-stage: row 0..63
  const int kq = (tid & 3) * 8;                // 8 k's
  const int kB = tid >> 3;                     // B-stage: k 0..31
  const int n8 = (tid & 7) * 8;

  const int trow = tb + r;
  const int src = flip ? (SEQ - 1 - trow) : trow;

  for (int k0 = 0; k0 < EMBD; k0 += 32) {
    const float* xp = X + (size_t)src * EMBD + k0 + kq;
    float4 xa = *(const float4*)xp;
    float4 xb = *(const float4*)(xp + 4);
    As[kq + 0][r] = xa.x; As[kq + 1][r] = xa.y; As[kq + 2][r] = xa.z; As[kq + 3][r] = xa.w;
    As[kq + 4][r] = xb.x; As[kq + 5][r] = xb.y; As[kq + 6][r] = xb.z; As[kq + 7][r] = xb.w;
    const float* wp = WT + (size_t)(k0 + kB) * 1024 + cb + n8;
    *(float4*)&Bs[kB][n8]     = *(const float4*)wp;
    *(float4*)&Bs[kB][n8 + 4] = *(const float4*)(wp + 4);
    __syncthreads();
    #pragma unroll
    for (int k = 0; k < 32; ++k) {
      float4 av = *(const float4*)&As[k][ty * 4];
      float4 bv = *(const float4*)&Bs[k][tx * 4];
      acc[0][0] = fmaf(av.x, bv.x, acc[0][0]); acc[0][1] = fmaf(av.x, bv.y, acc[0][1]);
      acc[0][2] = fmaf(av.x, bv.z, acc[0][2]); acc[0][3] = fmaf(av.x, bv.w, acc[0][3]);
      acc[1][0] = fmaf(av.y, bv.x, acc[1][0]); acc[1][1] = fmaf(av.y, bv.y, acc[1][1]);
      acc[1][2] = fmaf(av.y, bv.z, acc[1][2]); acc[1][3] = fmaf(av.y, bv.w, acc[1][3]);
      acc[2][0] = fmaf(av.z, bv.x, acc[2][0]); acc[2][1] = fmaf(av.z, bv.y, acc[2][1]);
      acc[2][2] = fmaf(av.z, bv.z, acc[2][2]); acc[2][3] = fmaf(av.z, bv.w, acc[2][3]);
      acc[3][0] = fmaf(av.w, bv.x, acc[3][0]); acc[3][1] = fmaf(av.w, bv.y, acc[3][1]);
      acc[3][2] = fmaf(av.w, bv.z, acc[3][2]); acc[3][3] = fmaf(av.w, bv.w, acc[3][3]);
    }
    __syncthreads();
  }
  float4 bz = *(const float4*)&bsum[cb + tx * 4];
  #pragma unroll
  for (int mm = 0; mm < 4; ++mm) {
    int t = tb + ty * 4 + mm;
    float4 v = { acc[mm][0] + bz.x, acc[mm][1] + bz.y, acc[mm][2] + bz.z, acc[mm][3] + bz.w };
    if (!flip) *(float4*)&Gf[(size_t)t * GATES + cb + tx * 4] = v;
    else       *(float4*)&Gb[(size_t)t * GATES + (cb - GATES) + tx * 4] = v;
  }
}

// ---------------- the serial LSTM recurrence (1 block per direction) ----------------
// Thread g -> hidden j = g>>2, quad-slot q = g&3. Each thread computes partial
// dot-products for ALL 4 gates of j over k-quarter [32q, 32q+32) in packed f16
// (64 __hfma2 vs 128 f32 FMA), reading only 64 B of h from LDS per step
// (8x less LDS-return traffic than full-h broadcast). Partials are combined by
// a DPP quad butterfly all-reduce; lane q then owns gate q (matching the
// quad-layout G), applies the activation, and quad-broadcasts the 4 gate
// values for the (redundant, deterministic) cell update. One barrier per step,
// double-buffered h.
__global__ __launch_bounds__(512, 2) void lstm_k(
    const float* __restrict__ whhf, const float* __restrict__ whhb,
    const float* __restrict__ Gf, const float* __restrict__ Gb,
    float* __restrict__ HF, float* __restrict__ HB) {
  const int dir = blockIdx.x;
  const float* __restrict__ G   = dir ? Gb : Gf;
  float* __restrict__ Hout      = dir ? HB : HF;
  const float* __restrict__ whh = dir ? whhb : whhf;
  const int g = threadIdx.x;
  const int j = g >> 2;         // hidden index 0..127
  const int q = g & 3;          // k-quarter AND own-gate index (i,f,g,o)
  const bool q0 = (q == 0);

  // weights: w2[gate][kk] = (W[gate*HD+j][q*32+2kk], W[..][q*32+2kk+1]) as half2
  __half2 w2[4][16];
  #pragma unroll
  for (int gi = 0; gi < 4; ++gi) {
    const float* wr = whh + (size_t)(gi * HD + j) * HD + q * 32;
    #pragma unroll
    for (int kk = 0; kk < 16; ++kk)
      w2[gi][kk] = __halves2half2(__float2half_rn(wr[2 * kk]),
                                  __float2half_rn(wr[2 * kk + 1]));
  }

  // unified activation for own gate q: sigmoid, except gate 2 = tanh = 2*sig(2x)-1
  const float mm = (q == 2) ? -LOG2E2 : -LOG2E;
  const float aa = (q == 2) ? 2.0f : 1.0f;
  const float bb = (q == 2) ? -1.0f : 0.0f;

  // h in f16, quarters padded to 48-half (96 B) stride -> conflict-free b128 reads
  constexpr int QS = 48;
  __shared__ __align__(16) __half hshA[4 * QS], hshB[4 * QS];
  if (g < 4 * QS) { hshA[g] = __float2half_rn(0.0f); }

  float cst = 0.0f;

  // 2-deep prefetch of per-step input projection (quad layout, coalesced)
  const float* gp = G + g;
  float gc  = gp[0];
  float gn1 = gp[GATES];
  gp += 2 * GATES;

  float* hout = Hout + (size_t)(dir ? (SEQ - 1) : 0) * HD + j;
  const ptrdiff_t hstep = dir ? -(ptrdiff_t)HD : (ptrdiff_t)HD;

  // h write slot for this thread's j (only q==0 writes)
  const int wslot = (j >> 5) * QS + (j & 31);

  lds_barrier();

  auto step = [&](const __half* hrd, __half* hwr) {
    float gcur = gc; gc = gn1; gn1 = *gp; gp += GATES;

    // read own 32-half quarter of h: 4 x b128
    const float4* hq = (const float4*)(hrd + q * QS);
    float4 r0 = hq[0], r1 = hq[1], r2 = hq[2], r3 = hq[3];
    const __half2* h0 = (const __half2*)&r0;
    const __half2* h1 = (const __half2*)&r1;
    const __half2* h2 = (const __half2*)&r2;
    const __half2* h3 = (const __half2*)&r3;

    __half2 z2 = __float2half2_rn(0.0f);
    __half2 a0 = z2, a1 = z2, a2 = z2, a3 = z2;
    #pragma unroll
    for (int i = 0; i < 4; ++i) {
      a0 = __hfma2(w2[0][i], h0[i], a0);  a1 = __hfma2(w2[1][i], h0[i], a1);
      a2 = __hfma2(w2[2][i], h0[i], a2);  a3 = __hfma2(w2[3][i], h0[i], a3);
      a0 = __hfma2(w2[0][4 + i], h1[i], a0);  a1 = __hfma2(w2[1][4 + i], h1[i], a1);
      a2 = __hfma2(w2[2][4 + i], h1[i], a2);  a3 = __hfma2(w2[3][4 + i], h1[i], a3);
      a0 = __hfma2(w2[0][8 + i], h2[i], a0);  a1 = __hfma2(w2[1][8 + i], h2[i], a1);
      a2 = __hfma2(w2[2][8 + i], h2[i], a2);  a3 = __hfma2(w2[3][8 + i], h2[i], a3);
      a0 = __hfma2(w2[0][12 + i], h3[i], a0); a1 = __hfma2(w2[1][12 + i], h3[i], a1);
      a2 = __hfma2(w2[2][12 + i], h3[i], a2); a3 = __hfma2(w2[3][12 + i], h3[i], a3);
    }
    float p0 = __low2float(a0) + __high2float(a0);
    float p1 = __low2float(a1) + __high2float(a1);
    float p2 = __low2float(a2) + __high2float(a2);
    float p3 = __low2float(a3) + __high2float(a3);

    // quad butterfly all-reduce (each gate sum completed in every lane)
    p0 += quad_dpp<0xB1>(p0); p1 += quad_dpp<0xB1>(p1);
    p2 += quad_dpp<0xB1>(p2); p3 += quad_dpp<0xB1>(p3);
    p0 += quad_dpp<0x4E>(p0); p1 += quad_dpp<0x4E>(p1);
    p2 += quad_dpp<0x4E>(p2); p3 += quad_dpp<0x4E>(p3);

    // lane q owns gate q
    float t0 = (q & 1) ? p1 : p0;
    float t1 = (q & 1) ? p3 : p2;
    float pre = ((q & 2) ? t1 : t0) + gcur;
    float act = fmaf(aa, fast_rcp(1.0f + exp2f(pre * mm)), bb);

    float i_ = quad_dpp<0x00>(act);
    float f_ = quad_dpp<0x55>(act);
    float g_ = quad_dpp<0xAA>(act);
    float o_ = quad_dpp<0xFF>(act);
    cst = fmaf(f_, cst, i_ * g_);
    float th = fmaf(2.0f, fast_rcp(1.0f + exp2f(cst * -LOG2E2)), -1.0f);
    float hj = o_ * th;
    if (q0) { hwr[wslot] = __float2half_rn(hj); *hout = hj; }
    hout += hstep;
    lds_barrier();   // the ONLY barrier per step
  };

  for (int t = 0; t < SEQ; t += 2) {
    step(hshA, hshB);
    step(hshB, hshA);
  }
}

// ---------------- tag-space projection: feats = [hf|hb] @ w_tag^T + b_tag ----------------
__global__ void feats_k(const float* __restrict__ HF, const float* __restrict__ HB,
                        const float* __restrict__ wtag, const float* __restrict__ btag,
                        float* __restrict__ feats) {
  const int t = blockIdx.x, l = threadIdx.x;   // 64 lanes
  float2 a = ((const float2*)(HF + (size_t)t * HD))[l];
  float2 b = ((const float2*)(HB + (size_t)t * HD))[l];
  float p[NTAGS];
  #pragma unroll
  for (int n = 0; n < NTAGS; ++n) {
    const float* wr = wtag + (size_t)n * 256;
    float2 w0 = ((const float2*)wr)[l];
    float2 w1 = ((const float2*)(wr + HD))[l];
    p[n] = a.x * w0.x + a.y * w0.y + b.x * w1.x + b.y * w1.y;
  }
  #pragma unroll
  for (int n = 0; n < NTAGS; ++n) {
    float v = p[n];
    for (int off = 32; off > 0; off >>= 1) v += __shfl_down(v, off);
    if (l == 0) feats[(size_t)t * 16 + n] = v + btag[n];
  }
}

// ---------------- Viterbi forward + chunked parallel backtrace ----------------
__global__ __launch_bounds__(1024) void viterbi_k(
    const float* __restrict__ feats, const float* __restrict__ trans,
    unsigned char* __restrict__ bpg, float* __restrict__ out) {
  __shared__ int sh_M[64 * 16];
  __shared__ int sh_B[64];
  __shared__ int sh_best;
  const int tid = threadIdx.x;

  if (tid < 64) {                 // wave 0: serial forward pass, lane n = next-tag
    const int n = tid;
    const bool act = n < NTAGS;
    float Tn[NTAGS];
    #pragma unroll
    for (int p = 0; p < NTAGS; ++p) Tn[p] = act ? trans[n * NTAGS + p] : 0.0f;
    const float Tstop = act ? trans[TAG_STOP * NTAGS + n] : 0.0f;
    float fv = (n == TAG_START) ? 0.0f : NEGV;

    float fbuf[8];                // 8-deep feats prefetch (static indices)
    #pragma unroll
    for (int u = 0; u < 8; ++u) fbuf[u] = act ? feats[(size_t)u * 16 + n] : 0.0f;

    for (int t0 = 0; t0 < SEQ; t0 += 8) {
      #pragma unroll
      for (int u = 0; u < 8; ++u) {
        const int t = t0 + u;
        float ftc = fbuf[u];
        fbuf[u] = act ? feats[(size_t)(t + 8) * 16 + n] : 0.0f;  // padded rows
        float s[NTAGS];
        #pragma unroll
        for (int p = 0; p < NTAGS; ++p) s[p] = bcast_lane(fv, p) + Tn[p];
        float bv; int bi;
        argmax14(s, bv, bi);
        fv = bv + ftc;
        if (act) bpg[(size_t)t * 16 + n] = (unsigned char)bi;
      }
    }
    float tn = fv + Tstop;
    float tv[NTAGS];
    #pragma unroll
    for (int p = 0; p < NTAGS; ++p) tv[p] = bcast_lane(tn, p);
    if (n == 0) {
      float bv; int bi;
      argmax14(tv, bv, bi);
      out[0] = bv;                // score
      sh_best = bi;
    }
  }
  __syncthreads();                // full drain: bpg visible to block
  {                               // phase B: compose 128-step backpointer maps per chunk
    const int c = tid >> 4, k = tid & 15;
    if (c >= 1 && c < 64 && k < NTAGS) {
      int x = k;
      for (int i = 127; i >= 0; --i) x = bpg[((size_t)(c * 128 + i)) * 16 + x];
      sh_M[c * 16 + k] = x;
    }
  }
  __syncthreads();
  if (tid == 0) {                 // phase C: serial walk over 64 chunk boundaries
    int b = sh_best;
    sh_B[63] = b;
    for (int c = 63; c >= 1; --c) { b = sh_M[c * 16 + b]; sh_B[c - 1] = b; }
  }
  __syncthreads();
  if (tid < 64) {                 // phase D: chunks re-walk in parallel, emit path
    const int c = tid;
    int x = sh_B[c];
    out[1 + c * 128 + 127] = (float)x;
    for (int i = 127; i >= 1; --i) {
      x = bpg[((size_t)(c * 128 + i)) * 16 + x];
      out[1 + c * 128 + i - 1] = (float)x;
    }
  }
}

extern "C" void kernel_launch(void* const* d_in, const int* in_sizes, int n_in,
                              void* d_out, int out_size, void* d_ws, size_t ws_size,
                              hipStream_t stream) {
  (void)in_sizes; (void)n_in; (void)out_size; (void)ws_size;
  const int*   sent = (const int*)d_in[0];
  const float* emb  = (const float*)d_in[1];
  const float* wihf = (const float*)d_in[2];
  const float* whhf = (const float*)d_in[3];
  const float* bihf = (const float*)d_in[4];
  const float* bhhf = (const float*)d_in[5];
  const float* wihb = (const float*)d_in[6];
  const float* whhb = (const float*)d_in[7];
  const float* bihb = (const float*)d_in[8];
  const float* bhhb = (const float*)d_in[9];
  const float* wtag = (const float*)d_in[10];
  const float* btag = (const float*)d_in[11];
  const float* trans = (const float*)d_in[12];

  float* ws = (float*)d_ws;
  float* X    = ws + OFF_X;
  float* WT   = ws + OFF_WT;
  float* BS   = ws + OFF_BSUM;
  float* Gf   = ws + OFF_GF;
  float* Gb   = ws + OFF_GB;
  float* HF   = ws + OFF_HF;
  float* HB   = ws + OFF_HB;
  float* FE   = ws + OFF_FEATS;
  unsigned char* bpg = (unsigned char*)(ws + OFF_BP);
  float* out = (float*)d_out;

  prep_k<<<1025, 256, 0, stream>>>(wihf, wihb, bihf, bhhf, bihb, bhhb, WT, BS);
  gather_k<<<SEQ, 64, 0, stream>>>(sent, emb, X);
  gemm_k<<<dim3(16, 128), 256, 0, stream>>>(X, WT, BS, Gf, Gb);
  lstm_k<<<2, 512, 0, stream>>>(whhf, whhb, Gf, Gb, HF, HB);
  feats_k<<<SEQ, 64, 0, stream>>>(HF, HB, wtag, btag, FE);
  viterbi_k<<<1, 1024, 0, stream>>>(FE, trans, bpg, out);
}